// Round 1
// baseline (337.823 us; speedup 1.0000x reference)
//
#include <hip/hip_runtime.h>

#define N_NODES 50000
#define N_EDGES 600000
#define N_RELS  19
#define D_IN    128
#define D_HID   64
#define D_OUT   2
#define EDGE_TILES ((N_EDGES + 127) / 128 + N_RELS)   // 4707
#define SL_BLOCKS  ((N_NODES + 63) / 64)              // 782
#define PREP_ELEMS (N_RELS * D_HID * D_IN + 48 * 64 + D_HID * D_IN)  // 166912
#define PREP_BLOCKS ((PREP_ELEMS + 255) / 256)        // 652

typedef unsigned short u16;
typedef unsigned int   u32;
typedef __attribute__((ext_vector_type(8))) short sfrag;   // 8 bf16 (4 VGPRs)
typedef __attribute__((ext_vector_type(4))) float f32x4;   // 4 fp32 acc

__device__ __forceinline__ u16 f2bf(float f){
  union { float f; u32 i; } v; v.f = f;
  u32 r = v.i + 0x7fffu + ((v.i >> 16) & 1u);  // RNE
  return (u16)(r >> 16);
}
__device__ __forceinline__ float bf2f(u16 u){
  union { u32 i; float f; } v; v.i = ((u32)u) << 16; return v.f;
}

// Fused: feat->featb bf16 convert, rel histogram, dst histogram.
// (hists pre-zeroed by hipMemsetAsync on the stream)
__global__ __launch_bounds__(256) void k_fused_pre(const float* __restrict__ feat,
                                                   u16* __restrict__ featb,
                                                   const int* __restrict__ et,
                                                   const int* __restrict__ dst,
                                                   int* __restrict__ hist_rel,
                                                   int* __restrict__ hist_dst){
  int i = blockIdx.x * 256 + threadIdx.x;
  float2 f = ((const float2*)feat)[i];
  ((u32*)featb)[i] = (u32)f2bf(f.x) | ((u32)f2bf(f.y) << 16);
  if (blockIdx.x < (N_EDGES + 255) / 256) {      // block-uniform branch
    __shared__ int lh[N_RELS];
    int tid = threadIdx.x;
    if (tid < N_RELS) lh[tid] = 0;
    __syncthreads();
    int e = blockIdx.x * 256 + tid;
    if (e < N_EDGES) {
      atomicAdd(&lh[et[e]], 1);
      atomicAdd(&hist_dst[dst[e]], 1);
    }
    __syncthreads();
    if (tid < N_RELS && lh[tid]) atomicAdd(&hist_rel[tid], lh[tid]);
  }
}

// Blocks 0..195: msgbuf region allocation (wave prefix + one atomic per wave).
// Block 196: rel scan (offs/toff/cur_rel).
// Blocks 197..: weight transform (652 blocks covers PREP_ELEMS):
//   W1Tb [19][64][128]; W2allT [48][64] (rows 0..37 = W2[r,:,o] at row 2r+o,
//   rows 38..47 zero); loop1Tb [64][128].
__global__ __launch_bounds__(256) void k_alloc_scan(
    const int* __restrict__ hist_dst, int* __restrict__ dstart,
    int* __restrict__ cur_dst, int* __restrict__ gcnt,
    const int* __restrict__ hist_rel, int* __restrict__ offs,
    int* __restrict__ toff, int* __restrict__ cur_rel,
    const float* __restrict__ W1, const float* __restrict__ loop1,
    const float* __restrict__ W2, u16* __restrict__ W1Tb,
    u16* __restrict__ loop1Tb, u16* __restrict__ W2allT){
  if (blockIdx.x >= 197) {                      // ---- weight transform ----
    int idx = (blockIdx.x - 197) * 256 + threadIdx.x;
    const int T1 = N_RELS * D_HID * D_IN;       // 155648
    const int T2c = T1 + 48 * 64;               // 158720
    const int T3 = T2c + D_HID * D_IN;          // 166912
    if (idx < T1) {
      int r = idx / (D_HID * D_IN);
      int t = idx - r * (D_HID * D_IN);
      int j = t >> 7, d = t & 127;
      W1Tb[idx] = f2bf(W1[(r * D_IN + d) * D_HID + j]);
    } else if (idx < T2c) {
      int k2 = idx - T1;
      int n = k2 >> 6, k = k2 & 63;
      float val = 0.f;
      if (n < N_RELS * D_OUT) {
        int r = n >> 1, o = n & 1;
        val = W2[(r * D_HID + k) * D_OUT + o];
      }
      W2allT[k2] = f2bf(val);
    } else if (idx < T3) {
      int k2 = idx - T2c;
      int j = k2 >> 7, d = k2 & 127;
      loop1Tb[k2] = f2bf(loop1[d * D_HID + j]);
    }
    return;
  }
  if (blockIdx.x == 196) {                      // ---- rel scan ----
    if (threadIdx.x == 0) {
      int acc = 0, tacc = 0;
      offs[0] = 0; toff[0] = 0;
      for (int r = 0; r < N_RELS; ++r) {
        cur_rel[r] = acc;
        int c = hist_rel[r];
        acc += c;                offs[r + 1] = acc;
        tacc += (c + 127) >> 7;  toff[r + 1] = tacc;
      }
    }
    return;
  }
  // ---- dst region allocation ----
  __shared__ int wbase[4];
  int tid = threadIdx.x, lane = tid & 63, wv = tid >> 6;
  int n = blockIdx.x * 256 + tid;
  int v = (n < N_NODES) ? hist_dst[n] : 0;
  int x = v;
  #pragma unroll
  for (int o = 1; o < 64; o <<= 1) { int u = __shfl_up(x, o); if (lane >= o) x += u; }
  if (lane == 63) wbase[wv] = atomicAdd(gcnt, x);   // x = wave total
  __syncthreads();
  int start = wbase[wv] + x - v;
  if (n < N_NODES) { dstart[n] = start; cur_dst[n] = start; }
}

__global__ __launch_bounds__(256) void k_scatter_rel(const int* __restrict__ et,
                                                     int* __restrict__ cursor,
                                                     int* __restrict__ perm){
  __shared__ int lh[N_RELS], base[N_RELS];
  int tid = threadIdx.x;
  if (tid < N_RELS) lh[tid] = 0;
  __syncthreads();
  int e = blockIdx.x * 256 + tid;
  int r = 0, my = 0;
  bool valid = e < N_EDGES;
  if (valid) { r = et[e]; my = atomicAdd(&lh[r], 1); }
  __syncthreads();
  if (tid < N_RELS && lh[tid]) base[tid] = atomicAdd(&cursor[tid], lh[tid]);
  __syncthreads();
  if (valid) perm[base[r] + my] = e;
}

// Merged: blocks < EDGE_TILES run layer-1 edge tiles (128 edges, K=128 bf16 MFMA,
// A fragments gathered DIRECTLY global->VGPR, only B staged in LDS; accumulator
// packed to bf16 in-register (shfl_xor pair exchange) into a bf16 msg LDS tile,
// then coalesced 128B row write-out). Blocks >= EDGE_TILES: dense self-loop GEMM
// (agg1f = feat @ loop1 + b1), A fragments also direct from global.
// LDS = 17408 (Bls) + 18432 (msg bf16) + 512 (posIds) = 36352 -> 4 blocks/CU.
__global__ __launch_bounds__(256) void k_se1(
    const u16* __restrict__ featb, const u16* __restrict__ W1Tb,
    const u16* __restrict__ loop1Tb, const float* __restrict__ b1,
    const int* __restrict__ src, const int* __restrict__ dst,
    const int* __restrict__ perm, const int* __restrict__ offs,
    const int* __restrict__ toff, int* __restrict__ cur_dst,
    u16* __restrict__ msgbuf, float* __restrict__ agg1f){
  __shared__ __align__(16) u16 Bls[64][136];    // 17408 B
  __shared__ __align__(16) u16 msg[128][72];    // 18432 B (stride 144B, 16B-mult)
  __shared__ int posIds[128];
  int tid = threadIdx.x, lane = tid & 63, w = tid >> 6;
  int r16 = lane & 15, c4 = lane >> 4;

  if (blockIdx.x >= EDGE_TILES) {               // ---- self-loop path ----
    int base = (blockIdx.x - EDGE_TILES) * 64;
    { int j = tid >> 2, seg = tid & 3;
      const uint4* g = (const uint4*)(loop1Tb + j * 128) + seg * 4;
      uint4* d = (uint4*)&Bls[j][seg * 32];
      d[0] = g[0]; d[1] = g[1]; d[2] = g[2]; d[3] = g[3]; }
    int arow = base + w * 16 + r16; if (arow >= N_NODES) arow = N_NODES - 1;
    sfrag aF[4];
    #pragma unroll
    for (int kk = 0; kk < 4; ++kk)
      aF[kk] = *(const sfrag*)(featb + (size_t)arow * D_IN + kk * 32 + c4 * 8);
    __syncthreads();
    #pragma unroll
    for (int ct = 0; ct < 4; ++ct) {
      f32x4 acc = {0.f, 0.f, 0.f, 0.f};
      #pragma unroll
      for (int kk = 0; kk < 4; ++kk) {
        sfrag bF = *(const sfrag*)&Bls[ct * 16 + r16][kk * 32 + c4 * 8];
        acc = __builtin_amdgcn_mfma_f32_16x16x32_bf16(aF[kk], bF, acc, 0, 0, 0);
      }
      int col = ct * 16 + r16;
      float bias = b1[col];
      #pragma unroll
      for (int reg = 0; reg < 4; ++reg) {
        int orow = base + w * 16 + c4 * 4 + reg;
        if (orow < N_NODES) agg1f[(size_t)orow * D_HID + col] = acc[reg] + bias;
      }
    }
    return;
  }

  // ---- edge-tile path ----
  int b = blockIdx.x;
  unsigned long long mm = __ballot((lane < N_RELS) && (b >= toff[lane + 1]));
  int rel = __popcll(mm);
  if (rel >= N_RELS) return;                    // uniform pad-tile exit
  int ts = offs[rel] + ((b - toff[rel]) << 7);
  int vc = offs[rel + 1] - ts; if (vc > 128) vc = 128;

  // issue per-row msgbuf position atomic EARLY; consume after MFMA (hides RTT)
  int myPos = -1;
  if (tid < 128 && tid < vc) {
    int e = perm[ts + tid];
    myPos = atomicAdd(&cur_dst[dst[e]], 1);
  }
  { // B tile: W1Tb[rel], 64 x 128 bf16 (16 KB)
    int j = tid >> 2, seg = tid & 3;
    const uint4* g = (const uint4*)(W1Tb + ((size_t)rel * 64 + j) * 128) + seg * 4;
    uint4* d = (uint4*)&Bls[j][seg * 32];
    d[0] = g[0]; d[1] = g[1]; d[2] = g[2]; d[3] = g[3];
  }
  // A fragments direct global->VGPR: 4 lanes/row read contiguous 64B chunks
  sfrag aF[2][4];
  #pragma unroll
  for (int mt = 0; mt < 2; ++mt) {
    int row = w * 32 + mt * 16 + r16;
    int rr = row < vc ? row : vc - 1;
    int s = src[perm[ts + rr]];
    const u16* ap = featb + (size_t)s * D_IN + c4 * 8;
    #pragma unroll
    for (int kk = 0; kk < 4; ++kk)
      aF[mt][kk] = *(const sfrag*)(ap + kk * 32);
  }
  __syncthreads();
  #pragma unroll
  for (int ct = 0; ct < 4; ++ct) {
    sfrag bF[4];
    #pragma unroll
    for (int kk = 0; kk < 4; ++kk)
      bF[kk] = *(const sfrag*)&Bls[ct * 16 + r16][kk * 32 + c4 * 8];
    #pragma unroll
    for (int mt = 0; mt < 2; ++mt) {
      f32x4 acc = {0.f, 0.f, 0.f, 0.f};
      #pragma unroll
      for (int kk = 0; kk < 4; ++kk)
        acc = __builtin_amdgcn_mfma_f32_16x16x32_bf16(aF[mt][kk], bF[kk], acc, 0, 0, 0);
      // pack adjacent cols (r16, r16^1) to one u32 of 2xbf16 via shfl_xor
      #pragma unroll
      for (int reg = 0; reg < 4; ++reg) {
        float v = acc[reg];
        float o = __shfl_xor(v, 1);
        float lo = (lane & 1) ? o : v;
        float hi = (lane & 1) ? v : o;
        u32 pk = (u32)f2bf(lo) | ((u32)f2bf(hi) << 16);
        if (!(lane & 1)) {
          int orow = w * 32 + mt * 16 + c4 * 4 + reg;  // D: col=lane&15, row=(lane>>4)*4+reg
          *(u32*)&msg[orow][ct * 16 + r16] = pk;
        }
      }
    }
  }
  if (tid < 128) posIds[tid] = myPos;
  __syncthreads();
  // coalesced bf16 row write-out (wave-private rows were packed above)
  { int row = tid >> 1, half = tid & 1;
    int pos = posIds[row];
    if (pos >= 0) {
      const uint4* mr = (const uint4*)&msg[row][half * 32];
      uint4* d = (uint4*)(msgbuf + (size_t)pos * D_HID + half * 32);
      d[0] = mr[0]; d[1] = mr[1]; d[2] = mr[2]; d[3] = mr[3];
    } }
}

// Fused: message aggregation (one node per wave) + self-loop + relu -> h1b,
// plus layer-2 self-loop: out[n,:] = h1 @ loop2 + b2 (full init of out).
__global__ __launch_bounds__(256) void k_agg_relu_self2(
    const u16* __restrict__ msgbuf, const int* __restrict__ dstart,
    const int* __restrict__ cnt, const float* __restrict__ agg1f,
    const float* __restrict__ loop2, const float* __restrict__ b2,
    u16* __restrict__ h1b, float* __restrict__ out){
  int wv = threadIdx.x >> 6, lane = threadIdx.x & 63;
  int n = blockIdx.x * 4 + wv;
  int s = dstart[n], epos = s + cnt[n];
  int h = lane >> 5, c = lane & 31;
  float a0 = 0.f, a1 = 0.f;
  for (int i = s + h; i < epos; i += 2) {
    u32 v = ((const u32*)msgbuf)[(size_t)i * 32 + c];
    a0 += bf2f((u16)(v & 0xffffu));
    a1 += bf2f((u16)(v >> 16));
  }
  a0 += __shfl_down(a0, 32);
  a1 += __shfl_down(a1, 32);
  float p0 = 0.f, p1 = 0.f;
  if (h == 0) {
    float2 sl = ((const float2*)(agg1f + (size_t)n * D_HID))[c];
    float v0 = a0 + sl.x, v1 = a1 + sl.y;
    v0 = v0 > 0.f ? v0 : 0.f;
    v1 = v1 > 0.f ? v1 : 0.f;
    ((u32*)h1b)[(size_t)n * 32 + c] = (u32)f2bf(v0) | ((u32)f2bf(v1) << 16);
    float2 w0 = ((const float2*)loop2)[2 * c];
    float2 w1 = ((const float2*)loop2)[2 * c + 1];
    p0 = v0 * w0.x + v1 * w1.x;
    p1 = v0 * w0.y + v1 * w1.y;
  }
  #pragma unroll
  for (int off = 16; off; off >>= 1) {
    p0 += __shfl_down(p0, off);
    p1 += __shfl_down(p1, off);
  }
  if (lane == 0) {
    out[n * 2]     = p0 + b2[0];
    out[n * 2 + 1] = p1 + b2[1];
  }
}

// Layer-2 dense per-rel transform of ALL nodes: T2[n][2r+o] = sum_k h1[n,k]*W2[r,k,o].
// [50000 x 64] @ [64 x 48(pad)] skinny bf16 MFMA GEMM; T2 stride 40 f32.
__global__ __launch_bounds__(256) void k_t2(
    const u16* __restrict__ h1b, const u16* __restrict__ W2allT,
    float* __restrict__ T2){
  __shared__ __align__(16) u16 Bls[48][72];     // 48x64 bf16, padded
  int tid = threadIdx.x, lane = tid & 63, w = tid >> 6;
  int r16 = lane & 15, c4 = lane >> 4;
  for (int idx = tid; idx < 48 * 8; idx += 256) {   // 384 uint4
    int row = idx >> 3, q = idx & 7;
    ((uint4*)&Bls[row][0])[q] = ((const uint4*)W2allT)[idx];
  }
  int base = blockIdx.x * 64;
  int arow = base + w * 16 + r16; if (arow >= N_NODES) arow = N_NODES - 1;
  sfrag aF[2];
  #pragma unroll
  for (int kk = 0; kk < 2; ++kk)
    aF[kk] = *(const sfrag*)(h1b + (size_t)arow * D_HID + kk * 32 + c4 * 8);
  __syncthreads();
  #pragma unroll
  for (int ct = 0; ct < 3; ++ct) {
    f32x4 acc = {0.f, 0.f, 0.f, 0.f};
    #pragma unroll
    for (int kk = 0; kk < 2; ++kk) {
      sfrag bF = *(const sfrag*)&Bls[ct * 16 + r16][kk * 32 + c4 * 8];
      acc = __builtin_amdgcn_mfma_f32_16x16x32_bf16(aF[kk], bF, acc, 0, 0, 0);
    }
    int col = ct * 16 + r16;
    if (col < N_RELS * D_OUT) {
      #pragma unroll
      for (int reg = 0; reg < 4; ++reg) {
        int orow = base + w * 16 + c4 * 4 + reg;
        if (orow < N_NODES) T2[(size_t)orow * 40 + col] = acc[reg];
      }
    }
  }
}

// Layer-2 edge pass: 8B gather from T2 per edge + 2 f32 atomics into out.
__global__ __launch_bounds__(256) void k_edge2(
    const float* __restrict__ T2, const int* __restrict__ src,
    const int* __restrict__ dst, const int* __restrict__ et,
    float* __restrict__ out){
  int e = blockIdx.x * 256 + threadIdx.x;
  if (e >= N_EDGES) return;
  int s = src[e], d = dst[e], r = et[e];
  float2 v = *(const float2*)(T2 + (size_t)s * 40 + r * 2);
  atomicAdd(&out[d * 2],     v.x);
  atomicAdd(&out[d * 2 + 1], v.y);
}

extern "C" void kernel_launch(void* const* d_in, const int* in_sizes, int n_in,
                              void* d_out, int out_size, void* d_ws, size_t ws_size,
                              hipStream_t stream){
  const float* feat  = (const float*)d_in[0];
  const float* W1    = (const float*)d_in[1];
  const float* loop1 = (const float*)d_in[2];
  const float* b1    = (const float*)d_in[3];
  const float* W2    = (const float*)d_in[4];
  const float* loop2 = (const float*)d_in[5];
  const float* b2    = (const float*)d_in[6];
  const int* src     = (const int*)d_in[7];
  const int* dst     = (const int*)d_in[8];
  const int* et      = (const int*)d_in[9];
  float* out = (float*)d_out;

  // workspace layout (16B-aligned), ~112 MB total.
  // hist_rel/gcnt/hist_dst are contiguous -> single memset zeroes all three.
  char* w = (char*)d_ws;
  u16*   W1Tb     = (u16*)(w);                   //  311296
  u16*   W2allT   = (u16*)(w + 311296);          //    6144 (in old W2Tb slot)
  u16*   loop1Tb  = (u16*)(w + 350208);          //   16384
  int*   hist_rel = (int*)(w + 366592);          //     128 ┐
  int*   gcnt     = (int*)(w + 366720);          //     128 ├ zeroed by memset (200256 B)
  int*   hist_dst = (int*)(w + 366848);          //  200000 ┘
  int*   offs     = (int*)(w + 566848);          //     128
  int*   toff     = (int*)(w + 566976);          //     128
  int*   cur_rel  = (int*)(w + 567104);          //     128
  int*   dstart   = (int*)(w + 567232);          //  200000
  int*   cur_dst  = (int*)(w + 767232);          //  200000
  int*   perm     = (int*)(w + 967232);          // 2400000
  u16*   featb    = (u16*)(w + 3367232);         // 12.8 MB (T2 aliases: featb dead after k_se1)
  float* T2f      = (float*)(w + 3367232);       //  8.0 MB (50000 x 40 f32)
  float* agg1f    = (float*)(w + 16167232);      // 12.8 MB
  u16*   h1b      = (u16*)(w + 28967232);        //  6.4 MB
  u16*   msgbuf   = (u16*)(w + 35367232);        // 76.8 MB -> 112167232

  hipMemsetAsync(w + 366592, 0, 200256, stream);
  k_fused_pre     <<<12500, 256, 0, stream>>>(feat, featb, et, dst, hist_rel, hist_dst);
  k_alloc_scan    <<<197 + PREP_BLOCKS, 256, 0, stream>>>(
                      hist_dst, dstart, cur_dst, gcnt, hist_rel, offs, toff, cur_rel,
                      W1, loop1, W2, W1Tb, loop1Tb, W2allT);
  k_scatter_rel   <<<2344,  256, 0, stream>>>(et, cur_rel, perm);
  k_se1           <<<EDGE_TILES + SL_BLOCKS, 256, 0, stream>>>(
                      featb, W1Tb, loop1Tb, b1, src, dst, perm, offs, toff,
                      cur_dst, msgbuf, agg1f);
  k_agg_relu_self2<<<12500, 256, 0, stream>>>(msgbuf, dstart, hist_dst, agg1f,
                                              loop2, b2, h1b, out);
  k_t2            <<<SL_BLOCKS, 256, 0, stream>>>(h1b, W2allT, T2f);
  k_edge2         <<<(N_EDGES + 255) / 256, 256, 0, stream>>>(T2f, src, dst, et, out);
}

// Round 2
// 304.736 us; speedup vs baseline: 1.1086x; 1.1086x over previous
//
#include <hip/hip_runtime.h>

#define N_NODES 50000
#define N_EDGES 600000
#define N_RELS  19
#define D_IN    128
#define D_HID   64
#define D_OUT   2
#define BSH     9                                   // src bucket = 512 nodes
#define NB      ((N_NODES + 511) >> 9)              // 98
#define NSEG    (NB * N_RELS)                       // 1862
#define NTILE_CAP (NSEG + (N_EDGES + 127) / 128)    // 6550 (hard upper bound)
#define SL_BLOCKS  ((N_NODES + 63) / 64)            // 782
#define PREP_ELEMS (N_RELS * D_HID * D_IN + 48 * 64 + D_HID * D_IN)  // 166912
#define PREP_BLOCKS ((PREP_ELEMS + 255) / 256)      // 652

typedef unsigned short u16;
typedef unsigned int   u32;
typedef __attribute__((ext_vector_type(8))) short sfrag;   // 8 bf16 (4 VGPRs)
typedef __attribute__((ext_vector_type(4))) float f32x4;   // 4 fp32 acc

__device__ __forceinline__ u16 f2bf(float f){
  union { float f; u32 i; } v; v.f = f;
  u32 r = v.i + 0x7fffu + ((v.i >> 16) & 1u);  // RNE
  return (u16)(r >> 16);
}
__device__ __forceinline__ float bf2f(u16 u){
  union { u32 i; float f; } v; v.i = ((u32)u) << 16; return v.f;
}
__device__ __forceinline__ u32 pack2(float lo, float hi){
  return (u32)f2bf(lo) | ((u32)f2bf(hi) << 16);
}

// Fused: feat->featb bf16 convert, (src-bucket,rel) segment histogram, dst histogram.
// seg_hist entries padded to one per 64B line (x16) to spread atomic contention.
__global__ __launch_bounds__(256) void k_fused_pre(const float* __restrict__ feat,
                                                   u16* __restrict__ featb,
                                                   const int* __restrict__ src,
                                                   const int* __restrict__ et,
                                                   const int* __restrict__ dst,
                                                   int* __restrict__ seg_hist,
                                                   int* __restrict__ hist_dst){
  int i = blockIdx.x * 256 + threadIdx.x;
  float2 f = ((const float2*)feat)[i];
  ((u32*)featb)[i] = (u32)f2bf(f.x) | ((u32)f2bf(f.y) << 16);
  if (i < N_EDGES) {
    int key = (src[i] >> BSH) * N_RELS + et[i];
    atomicAdd(&seg_hist[key * 16], 1);
    atomicAdd(&hist_dst[dst[i]], 1);
  }
}

// Blocks 0..195: msgbuf region allocation (wave prefix + one atomic per wave).
// Block 196: segment scan + tile table (tseg/tstart/ntile).
// Blocks 197..: weight transform:
//   W1Tb [19][64][128]; W2allT [48][64] (row 2r+o = W2[r,:,o], rows 38..47 zero);
//   loop1Tb [64][128].
__global__ __launch_bounds__(256) void k_alloc_scan(
    const int* __restrict__ hist_dst, int* __restrict__ dstart,
    int* __restrict__ cur_dst, int* __restrict__ gcnt,
    const int* __restrict__ seg_hist, int* __restrict__ seg_off,
    int* __restrict__ cur_seg, int* __restrict__ ntile,
    int* __restrict__ tseg, int* __restrict__ tstart,
    const float* __restrict__ W1, const float* __restrict__ loop1,
    const float* __restrict__ W2, u16* __restrict__ W1Tb,
    u16* __restrict__ loop1Tb, u16* __restrict__ W2allT){
  if (blockIdx.x >= 197) {                      // ---- weight transform ----
    int idx = (blockIdx.x - 197) * 256 + threadIdx.x;
    const int T1 = N_RELS * D_HID * D_IN;       // 155648
    const int T2c = T1 + 48 * 64;               // 158720
    const int T3 = T2c + D_HID * D_IN;          // 166912
    if (idx < T1) {
      int r = idx / (D_HID * D_IN);
      int t = idx - r * (D_HID * D_IN);
      int j = t >> 7, d = t & 127;
      W1Tb[idx] = f2bf(W1[(r * D_IN + d) * D_HID + j]);
    } else if (idx < T2c) {
      int k2 = idx - T1;
      int n = k2 >> 6, k = k2 & 63;
      float val = 0.f;
      if (n < N_RELS * D_OUT) {
        int r = n >> 1, o = n & 1;
        val = W2[(r * D_HID + k) * D_OUT + o];
      }
      W2allT[k2] = f2bf(val);
    } else if (idx < T3) {
      int k2 = idx - T2c;
      int j = k2 >> 7, d = k2 & 127;
      loop1Tb[k2] = f2bf(loop1[d * D_HID + j]);
    }
    return;
  }
  if (blockIdx.x == 196) {                      // ---- segment scan + tile table ----
    __shared__ int se_s[256], st_s[256];
    int tid = threadIdx.x;
    const int PER = (NSEG + 255) / 256;         // 8
    int lo = tid * PER, hi = lo + PER; if (hi > NSEG) hi = NSEG; if (lo > NSEG) lo = NSEG;
    int se = 0, st = 0;
    for (int i = lo; i < hi; ++i) { int c = seg_hist[i * 16]; se += c; st += (c + 127) >> 7; }
    se_s[tid] = se; st_s[tid] = st;
    __syncthreads();
    if (tid == 0) {
      int a = 0, b = 0;
      for (int j = 0; j < 256; ++j) { int x = se_s[j], y = st_s[j]; se_s[j] = a; st_s[j] = b; a += x; b += y; }
      ntile[0] = b;
    }
    __syncthreads();
    int eo = se_s[tid], to = st_s[tid];
    for (int i = lo; i < hi; ++i) {
      int c = seg_hist[i * 16];
      seg_off[i] = eo; cur_seg[i * 16] = eo;
      int nt = (c + 127) >> 7;
      for (int k = 0; k < nt; ++k) { tseg[to + k] = i; tstart[to + k] = eo + (k << 7); }
      eo += c; to += nt;
    }
    if (hi == NSEG) seg_off[NSEG] = eo;         // == N_EDGES
    return;
  }
  // ---- dst region allocation ----
  __shared__ int wbase[4];
  int tid = threadIdx.x, lane = tid & 63, wv = tid >> 6;
  int n = blockIdx.x * 256 + tid;
  int v = (n < N_NODES) ? hist_dst[n] : 0;
  int x = v;
  #pragma unroll
  for (int o = 1; o < 64; o <<= 1) { int u = __shfl_up(x, o); if (lane >= o) x += u; }
  if (lane == 63) wbase[wv] = atomicAdd(gcnt, x);   // x = wave total
  __syncthreads();
  int start = wbase[wv] + x - v;
  if (n < N_NODES) { dstart[n] = start; cur_dst[n] = start; }
}

// Scatter edges into perm, grouped by (src-bucket, rel) segment.
__global__ __launch_bounds__(256) void k_scatter(const int* __restrict__ src,
                                                 const int* __restrict__ et,
                                                 int* __restrict__ cur_seg,
                                                 int* __restrict__ perm){
  int e = blockIdx.x * 256 + threadIdx.x;
  if (e >= N_EDGES) return;
  int key = (src[e] >> BSH) * N_RELS + et[e];
  int p = atomicAdd(&cur_seg[key * 16], 1);
  perm[p] = e;
}

// Blocks < NTILE_CAP: layer-1 edge tiles (128 edges, rel-pure, src within a 512-node
// bucket -> featb gathers are L2-resident). XCD-bijective chunked swizzle keeps
// consecutive tiles on the same XCD so each featb row fills exactly one L2 and is
// reused ~12x. Blocks >= NTILE_CAP: dense self-loop GEMM -> agg1b (bf16, LDS-packed
// coalesced writeout).
__global__ __launch_bounds__(256) void k_se1(
    const u16* __restrict__ featb, const u16* __restrict__ W1Tb,
    const u16* __restrict__ loop1Tb, const float* __restrict__ b1,
    const int* __restrict__ src, const int* __restrict__ dst,
    const int* __restrict__ perm, const int* __restrict__ seg_off,
    const int* __restrict__ ntile_p, const int* __restrict__ tseg,
    const int* __restrict__ tstart, int* __restrict__ cur_dst,
    int* __restrict__ srel, u16* __restrict__ msgbuf, u16* __restrict__ agg1b){
  __shared__ __align__(16) u16 Bls[64][136];    // 17408 B
  __shared__ __align__(16) u16 msg[128][72];    // 18432 B
  __shared__ int posIds[128];
  int tid = threadIdx.x, lane = tid & 63, w = tid >> 6;
  int r16 = lane & 15, c4 = lane >> 4;

  if (blockIdx.x >= NTILE_CAP) {                // ---- self-loop path ----
    int base = (blockIdx.x - NTILE_CAP) * 64;
    { int j = tid >> 2, seg = tid & 3;
      const uint4* g = (const uint4*)(loop1Tb + j * 128) + seg * 4;
      uint4* d = (uint4*)&Bls[j][seg * 32];
      d[0] = g[0]; d[1] = g[1]; d[2] = g[2]; d[3] = g[3]; }
    int arow = base + w * 16 + r16; if (arow >= N_NODES) arow = N_NODES - 1;
    sfrag aF[4];
    #pragma unroll
    for (int kk = 0; kk < 4; ++kk)
      aF[kk] = *(const sfrag*)(featb + (size_t)arow * D_IN + kk * 32 + c4 * 8);
    __syncthreads();
    #pragma unroll
    for (int ct = 0; ct < 4; ++ct) {
      f32x4 acc = {0.f, 0.f, 0.f, 0.f};
      #pragma unroll
      for (int kk = 0; kk < 4; ++kk) {
        sfrag bF = *(const sfrag*)&Bls[ct * 16 + r16][kk * 32 + c4 * 8];
        acc = __builtin_amdgcn_mfma_f32_16x16x32_bf16(aF[kk], bF, acc, 0, 0, 0);
      }
      int col = ct * 16 + r16;
      float bias = b1[col];
      #pragma unroll
      for (int reg = 0; reg < 4; ++reg) {
        float v = acc[reg] + bias;
        float o = __shfl_xor(v, 1);
        if (!(lane & 1)) {
          int orow = w * 16 + c4 * 4 + reg;     // block-local 0..63
          *(u32*)&msg[orow][col] = pack2(v, o);
        }
      }
    }
    __syncthreads();
    { int row = tid >> 2, q = tid & 3;          // 4 threads/row, 32B each
      int n = base + row;
      if (n < N_NODES) {
        uint4 a0 = ((const uint4*)&msg[row][0])[q * 2];
        uint4 a1 = ((const uint4*)&msg[row][0])[q * 2 + 1];
        uint4* d = (uint4*)(agg1b + (size_t)n * D_HID + q * 16);
        d[0] = a0; d[1] = a1;
      } }
    return;
  }

  // ---- edge-tile path ----
  int nt = *ntile_p;
  int pb = blockIdx.x;
  if (pb >= nt) return;                         // pad blocks (cap > actual)
  // bijective XCD-chunked swizzle over [0, nt)  (xcd = pb & 7 hardware RR)
  int q8 = nt >> 3, r8 = nt & 7;
  int xcd = pb & 7, idx = pb >> 3;
  int b = (xcd < r8 ? xcd * (q8 + 1) : r8 * (q8 + 1) + (xcd - r8) * q8) + idx;

  int seg = tseg[b];
  int ts  = tstart[b];
  int vc  = seg_off[seg + 1] - ts; if (vc > 128) vc = 128;
  int rel = seg % N_RELS;

  // per-row msgbuf position atomic EARLY; also record (src,rel) for layer-2 finish
  int myPos = -1;
  if (tid < 128 && tid < vc) {
    int e = perm[ts + tid];
    int s2 = src[e];
    myPos = atomicAdd(&cur_dst[dst[e]], 1);
    srel[myPos] = (s2 << 5) | rel;
  }
  { // B tile: W1Tb[rel], 64 x 128 bf16 (16 KB)
    int j = tid >> 2, seg2 = tid & 3;
    const uint4* g = (const uint4*)(W1Tb + ((size_t)rel * 64 + j) * 128) + seg2 * 4;
    uint4* d = (uint4*)&Bls[j][seg2 * 32];
    d[0] = g[0]; d[1] = g[1]; d[2] = g[2]; d[3] = g[3];
  }
  // A fragments direct global->VGPR (L2-resident bucket window)
  sfrag aF[2][4];
  #pragma unroll
  for (int mt = 0; mt < 2; ++mt) {
    int row = w * 32 + mt * 16 + r16;
    int rr = row < vc ? row : vc - 1;
    int s = src[perm[ts + rr]];
    const u16* ap = featb + (size_t)s * D_IN + c4 * 8;
    #pragma unroll
    for (int kk = 0; kk < 4; ++kk)
      aF[mt][kk] = *(const sfrag*)(ap + kk * 32);
  }
  __syncthreads();
  #pragma unroll
  for (int ct = 0; ct < 4; ++ct) {
    sfrag bF[4];
    #pragma unroll
    for (int kk = 0; kk < 4; ++kk)
      bF[kk] = *(const sfrag*)&Bls[ct * 16 + r16][kk * 32 + c4 * 8];
    #pragma unroll
    for (int mt = 0; mt < 2; ++mt) {
      f32x4 acc = {0.f, 0.f, 0.f, 0.f};
      #pragma unroll
      for (int kk = 0; kk < 4; ++kk)
        acc = __builtin_amdgcn_mfma_f32_16x16x32_bf16(aF[mt][kk], bF[kk], acc, 0, 0, 0);
      #pragma unroll
      for (int reg = 0; reg < 4; ++reg) {
        float v = acc[reg];
        float o = __shfl_xor(v, 1);
        if (!(lane & 1)) {
          int orow = w * 32 + mt * 16 + c4 * 4 + reg;
          *(u32*)&msg[orow][ct * 16 + r16] = pack2(v, o);
        }
      }
    }
  }
  if (tid < 128) posIds[tid] = myPos;
  __syncthreads();
  { int row = tid >> 1, half = tid & 1;
    int pos = posIds[row];
    if (pos >= 0) {
      const uint4* mr = (const uint4*)&msg[row][half * 32];
      uint4* d = (uint4*)(msgbuf + (size_t)pos * D_HID + half * 32);
      d[0] = mr[0]; d[1] = mr[1]; d[2] = mr[2]; d[3] = mr[3];
    } }
}

// Fused: message aggregation (one node per wave) + self-loop + relu -> h1b,
// plus layer-2 self-loop: out[n,:] = h1 @ loop2 + b2 (full init of out).
__global__ __launch_bounds__(256) void k_agg_relu_self2(
    const u16* __restrict__ msgbuf, const int* __restrict__ dstart,
    const int* __restrict__ cnt, const u16* __restrict__ agg1b,
    const float* __restrict__ loop2, const float* __restrict__ b2,
    u16* __restrict__ h1b, float* __restrict__ out){
  int wv = threadIdx.x >> 6, lane = threadIdx.x & 63;
  int n = blockIdx.x * 4 + wv;
  int s = dstart[n], epos = s + cnt[n];
  int h = lane >> 5, c = lane & 31;
  float a0 = 0.f, a1 = 0.f;
  for (int i = s + h; i < epos; i += 2) {
    u32 v = ((const u32*)msgbuf)[(size_t)i * 32 + c];
    a0 += bf2f((u16)(v & 0xffffu));
    a1 += bf2f((u16)(v >> 16));
  }
  a0 += __shfl_down(a0, 32);
  a1 += __shfl_down(a1, 32);
  float p0 = 0.f, p1 = 0.f;
  if (h == 0) {
    u32 sv = ((const u32*)agg1b)[(size_t)n * 32 + c];
    float v0 = a0 + bf2f((u16)(sv & 0xffffu));
    float v1 = a1 + bf2f((u16)(sv >> 16));
    v0 = v0 > 0.f ? v0 : 0.f;
    v1 = v1 > 0.f ? v1 : 0.f;
    ((u32*)h1b)[(size_t)n * 32 + c] = (u32)f2bf(v0) | ((u32)f2bf(v1) << 16);
    float2 w0 = ((const float2*)loop2)[2 * c];
    float2 w1 = ((const float2*)loop2)[2 * c + 1];
    p0 = v0 * w0.x + v1 * w1.x;
    p1 = v0 * w0.y + v1 * w1.y;
  }
  #pragma unroll
  for (int off = 16; off; off >>= 1) {
    p0 += __shfl_down(p0, off);
    p1 += __shfl_down(p1, off);
  }
  if (lane == 0) {
    out[n * 2]     = p0 + b2[0];
    out[n * 2 + 1] = p1 + b2[1];
  }
}

// Layer-2 dense per-rel transform of ALL nodes: T2[n][2r+o] = sum_k h1[n,k]*W2[r,k,o].
// [50000 x 64] @ [64 x 48(pad)] skinny bf16 MFMA GEMM; T2 stride 40 f32.
__global__ __launch_bounds__(256) void k_t2(
    const u16* __restrict__ h1b, const u16* __restrict__ W2allT,
    float* __restrict__ T2){
  __shared__ __align__(16) u16 Bls[48][72];
  int tid = threadIdx.x, lane = tid & 63, w = tid >> 6;
  int r16 = lane & 15, c4 = lane >> 4;
  for (int idx = tid; idx < 48 * 8; idx += 256) {
    int row = idx >> 3, q = idx & 7;
    ((uint4*)&Bls[row][0])[q] = ((const uint4*)W2allT)[idx];
  }
  int base = blockIdx.x * 64;
  int arow = base + w * 16 + r16; if (arow >= N_NODES) arow = N_NODES - 1;
  sfrag aF[2];
  #pragma unroll
  for (int kk = 0; kk < 2; ++kk)
    aF[kk] = *(const sfrag*)(h1b + (size_t)arow * D_HID + kk * 32 + c4 * 8);
  __syncthreads();
  #pragma unroll
  for (int ct = 0; ct < 3; ++ct) {
    f32x4 acc = {0.f, 0.f, 0.f, 0.f};
    #pragma unroll
    for (int kk = 0; kk < 2; ++kk) {
      sfrag bF = *(const sfrag*)&Bls[ct * 16 + r16][kk * 32 + c4 * 8];
      acc = __builtin_amdgcn_mfma_f32_16x16x32_bf16(aF[kk], bF, acc, 0, 0, 0);
    }
    int col = ct * 16 + r16;
    if (col < N_RELS * D_OUT) {
      #pragma unroll
      for (int reg = 0; reg < 4; ++reg) {
        int orow = base + w * 16 + c4 * 4 + reg;
        if (orow < N_NODES) T2[(size_t)orow * 40 + col] = acc[reg];
      }
    }
  }
}

// Layer-2 finish, atomic-free: one wave per node; gather T2[src][2r..] for each
// of the node's msgbuf slots (via srel), reduce, add to out.
__global__ __launch_bounds__(256) void k_fin(
    const float* __restrict__ T2, const int* __restrict__ srel,
    const int* __restrict__ dstart, const int* __restrict__ cnt,
    float* __restrict__ out){
  int wv = threadIdx.x >> 6, lane = threadIdx.x & 63;
  int n = blockIdx.x * 4 + wv;
  int s = dstart[n], c = cnt[n];
  float ax = 0.f, ay = 0.f;
  for (int i = lane; i < c; i += 64) {
    int sr = srel[s + i];
    const float* p = T2 + (size_t)(sr >> 5) * 40 + (sr & 31) * 2;
    ax += p[0]; ay += p[1];
  }
  #pragma unroll
  for (int off = 32; off; off >>= 1) {
    ax += __shfl_down(ax, off);
    ay += __shfl_down(ay, off);
  }
  if (lane == 0) {
    out[n * 2]     += ax;
    out[n * 2 + 1] += ay;
  }
}

extern "C" void kernel_launch(void* const* d_in, const int* in_sizes, int n_in,
                              void* d_out, int out_size, void* d_ws, size_t ws_size,
                              hipStream_t stream){
  const float* feat  = (const float*)d_in[0];
  const float* W1    = (const float*)d_in[1];
  const float* loop1 = (const float*)d_in[2];
  const float* b1    = (const float*)d_in[3];
  const float* W2    = (const float*)d_in[4];
  const float* loop2 = (const float*)d_in[5];
  const float* b2    = (const float*)d_in[6];
  const int* src     = (const int*)d_in[7];
  const int* dst     = (const int*)d_in[8];
  const int* et      = (const int*)d_in[9];
  float* out = (float*)d_out;

  // workspace layout (16B-aligned), ~108.4 MB total.
  // seg_hist/gcnt/hist_dst contiguous -> single memset (319232 B).
  char* w = (char*)d_ws;
  u16*   W1Tb     = (u16*)(w);                   //  311296
  u16*   W2allT   = (u16*)(w + 311296);          //    6144
  u16*   loop1Tb  = (u16*)(w + 317440);          //   16384
  int*   seg_hist = (int*)(w + 333824);          //  119168 (1862 x 64B-padded) ┐
  int*   gcnt     = (int*)(w + 452992);          //      64                     ├ memset
  int*   hist_dst = (int*)(w + 453056);          //  200000                     ┘
  int*   seg_off  = (int*)(w + 653056);          //    7488
  int*   cur_seg  = (int*)(w + 660544);          //  119168 (64B-padded)
  int*   ntile    = (int*)(w + 779712);          //      64
  int*   tseg     = (int*)(w + 779776);          //   26240
  int*   tstart   = (int*)(w + 806016);          //   26240
  int*   dstart   = (int*)(w + 832256);          //  200000
  int*   cur_dst  = (int*)(w + 1032256);         //  200000
  int*   perm     = (int*)(w + 1232256);         // 2400000
  int*   srel     = (int*)(w + 3632256);         // 2400000
  u16*   featb    = (u16*)(w + 6032256);         // 12.8 MB (T2f aliases; featb dead after k_se1)
  float* T2f      = (float*)(w + 6032256);       //  8.0 MB (50000 x 40 f32)
  u16*   agg1b    = (u16*)(w + 18832256);        //  6.4 MB
  u16*   h1b      = (u16*)(w + 25232256);        //  6.4 MB
  u16*   msgbuf   = (u16*)(w + 31632256);        // 76.8 MB -> 108432256

  hipMemsetAsync(w + 333824, 0, 319232, stream);
  k_fused_pre     <<<12500, 256, 0, stream>>>(feat, featb, src, et, dst, seg_hist, hist_dst);
  k_alloc_scan    <<<197 + PREP_BLOCKS, 256, 0, stream>>>(
                      hist_dst, dstart, cur_dst, gcnt, seg_hist, seg_off, cur_seg,
                      ntile, tseg, tstart, W1, loop1, W2, W1Tb, loop1Tb, W2allT);
  k_scatter       <<<2344,  256, 0, stream>>>(src, et, cur_seg, perm);
  k_se1           <<<NTILE_CAP + SL_BLOCKS, 256, 0, stream>>>(
                      featb, W1Tb, loop1Tb, b1, src, dst, perm, seg_off, ntile,
                      tseg, tstart, cur_dst, srel, msgbuf, agg1b);
  k_agg_relu_self2<<<12500, 256, 0, stream>>>(msgbuf, dstart, hist_dst, agg1b,
                                              loop2, b2, h1b, out);
  k_t2            <<<SL_BLOCKS, 256, 0, stream>>>(h1b, W2allT, T2f);
  k_fin           <<<12500, 256, 0, stream>>>(T2f, srel, dstart, hist_dst, out);
}

// Round 3
// 302.398 us; speedup vs baseline: 1.1171x; 1.0077x over previous
//
#include <hip/hip_runtime.h>

#define N_NODES 50000
#define N_EDGES 600000
#define N_RELS  19
#define D_IN    128
#define D_HID   64
#define D_OUT   2
#define BSH     9                                   // src bucket = 512 nodes
#define NB      ((N_NODES + 511) >> 9)              // 98
#define NSEG    (NB * N_RELS)                       // 1862
#define SL_BLOCKS  ((N_NODES + 63) / 64)            // 782
#define PREP_ELEMS (N_RELS * D_HID * D_IN + 48 * 64 + D_HID * D_IN)  // 166912
#define PREP_BLOCKS ((PREP_ELEMS + 255) / 256)      // 652

typedef unsigned short u16;
typedef unsigned int   u32;
typedef __attribute__((ext_vector_type(8))) short sfrag;   // 8 bf16 (4 VGPRs)
typedef __attribute__((ext_vector_type(4))) float f32x4;   // 4 fp32 acc

__device__ __forceinline__ u16 f2bf(float f){
  union { float f; u32 i; } v; v.f = f;
  u32 r = v.i + 0x7fffu + ((v.i >> 16) & 1u);  // RNE
  return (u16)(r >> 16);
}
__device__ __forceinline__ float bf2f(u16 u){
  union { u32 i; float f; } v; v.i = ((u32)u) << 16; return v.f;
}
__device__ __forceinline__ u32 pack2(float lo, float hi){
  return (u32)f2bf(lo) | ((u32)f2bf(hi) << 16);
}

// Fused: feat->featb bf16 convert (float4), (src-bucket,rel) seg histogram, dst hist.
__global__ __launch_bounds__(256) void k_fused_pre(const float* __restrict__ feat,
                                                   u16* __restrict__ featb,
                                                   const int* __restrict__ src,
                                                   const int* __restrict__ et,
                                                   const int* __restrict__ dst,
                                                   int* __restrict__ seg_hist,
                                                   int* __restrict__ hist_dst){
  int i = blockIdx.x * 256 + threadIdx.x;          // 1.6M float4 elems
  float4 f = ((const float4*)feat)[i];
  uint2 p; p.x = pack2(f.x, f.y); p.y = pack2(f.z, f.w);
  ((uint2*)featb)[i] = p;
  if (i < N_EDGES) {
    int key = (src[i] >> BSH) * N_RELS + et[i];
    atomicAdd(&seg_hist[key * 16], 1);
    atomicAdd(&hist_dst[dst[i]], 1);
  }
}

// Blocks 0..195: msgbuf region allocation. Block 196: segment scan (seg_off/cur_seg).
// Blocks 197..: weight transform (W1Tb [19][64][128]; W2allT [48][64]; loop1Tb [64][128]).
__global__ __launch_bounds__(256) void k_alloc_scan(
    const int* __restrict__ hist_dst, int* __restrict__ dstart,
    int* __restrict__ cur_dst, int* __restrict__ gcnt,
    const int* __restrict__ seg_hist, int* __restrict__ seg_off,
    int* __restrict__ cur_seg,
    const float* __restrict__ W1, const float* __restrict__ loop1,
    const float* __restrict__ W2, u16* __restrict__ W1Tb,
    u16* __restrict__ loop1Tb, u16* __restrict__ W2allT){
  if (blockIdx.x >= 197) {                      // ---- weight transform ----
    int idx = (blockIdx.x - 197) * 256 + threadIdx.x;
    const int T1 = N_RELS * D_HID * D_IN;       // 155648
    const int T2c = T1 + 48 * 64;               // 158720
    const int T3 = T2c + D_HID * D_IN;          // 166912
    if (idx < T1) {
      int r = idx / (D_HID * D_IN);
      int t = idx - r * (D_HID * D_IN);
      int j = t >> 7, d = t & 127;
      W1Tb[idx] = f2bf(W1[(r * D_IN + d) * D_HID + j]);
    } else if (idx < T2c) {
      int k2 = idx - T1;
      int n = k2 >> 6, k = k2 & 63;
      float val = 0.f;
      if (n < N_RELS * D_OUT) {
        int r = n >> 1, o = n & 1;
        val = W2[(r * D_HID + k) * D_OUT + o];
      }
      W2allT[k2] = f2bf(val);
    } else if (idx < T3) {
      int k2 = idx - T2c;
      int j = k2 >> 7, d = k2 & 127;
      loop1Tb[k2] = f2bf(loop1[d * D_HID + j]);
    }
    return;
  }
  if (blockIdx.x == 196) {                      // ---- segment scan ----
    __shared__ int se_s[256];
    int tid = threadIdx.x;
    const int PER = (NSEG + 255) / 256;         // 8
    int lo = tid * PER, hi = lo + PER; if (hi > NSEG) hi = NSEG; if (lo > NSEG) lo = NSEG;
    int se = 0;
    for (int i = lo; i < hi; ++i) se += seg_hist[i * 16];
    se_s[tid] = se;
    __syncthreads();
    if (tid == 0) {
      int a = 0;
      for (int j = 0; j < 256; ++j) { int x = se_s[j]; se_s[j] = a; a += x; }
    }
    __syncthreads();
    int eo = se_s[tid];
    for (int i = lo; i < hi; ++i) {
      int c = seg_hist[i * 16];
      seg_off[i] = eo; cur_seg[i * 16] = eo;
      eo += c;
    }
    if (hi == NSEG) seg_off[NSEG] = eo;         // == N_EDGES
    return;
  }
  // ---- dst region allocation ----
  __shared__ int wbase[4];
  int tid = threadIdx.x, lane = tid & 63, wv = tid >> 6;
  int n = blockIdx.x * 256 + tid;
  int v = (n < N_NODES) ? hist_dst[n] : 0;
  int x = v;
  #pragma unroll
  for (int o = 1; o < 64; o <<= 1) { int u = __shfl_up(x, o); if (lane >= o) x += u; }
  if (lane == 63) wbase[wv] = atomicAdd(gcnt, x);   // x = wave total
  __syncthreads();
  int start = wbase[wv] + x - v;
  if (n < N_NODES) { dstart[n] = start; cur_dst[n] = start; }
}

// Scatter edges into perm, grouped by (src-bucket, rel) segment.
__global__ __launch_bounds__(256) void k_scatter(const int* __restrict__ src,
                                                 const int* __restrict__ et,
                                                 int* __restrict__ cur_seg,
                                                 int* __restrict__ perm){
  int e = blockIdx.x * 256 + threadIdx.x;
  if (e >= N_EDGES) return;
  int key = (src[e] >> BSH) * N_RELS + et[e];
  int p = atomicAdd(&cur_seg[key * 16], 1);
  perm[p] = e;
}

// Gather A-fragments + msgbuf slot atomic for one 128-edge tile (into registers).
__device__ __forceinline__ void gather_tile(
    const u16* __restrict__ featb, const int* __restrict__ src,
    const int* __restrict__ dst, const int* __restrict__ perm,
    int* __restrict__ cur_dst, int* __restrict__ srel,
    int ts, int c, int t0, int rel, int tid, int w, int r16, int c4,
    sfrag (&aN)[2][4], int& nextPos){
  int vc = c - t0; if (vc > 128) vc = 128;
  #pragma unroll
  for (int mt = 0; mt < 2; ++mt) {
    int row = w * 32 + mt * 16 + r16;
    int rr = row < vc ? row : vc - 1;
    int s = src[perm[ts + t0 + rr]];
    const u16* ap = featb + (size_t)s * D_IN + c4 * 8;
    #pragma unroll
    for (int kk = 0; kk < 4; ++kk)
      aN[mt][kk] = *(const sfrag*)(ap + kk * 32);
  }
  nextPos = -1;
  if (tid < 128 && tid < vc) {
    int e = perm[ts + t0 + tid];
    nextPos = atomicAdd(&cur_dst[dst[e]], 1);
    srel[nextPos] = (src[e] << 5) | rel;
  }
}

// Blocks < NSEG: one (src-bucket, rel) SEGMENT per block — B staged once, then a
// software-pipelined loop over the segment's 128-edge tiles: gathers + slot atomic
// for tile t+1 issue BEFORE the MFMA of tile t (latency hidden under compute).
// Blocks >= NSEG: dense self-loop GEMM -> agg1b.
__global__ __launch_bounds__(256, 4) void k_se1(
    const u16* __restrict__ featb, const u16* __restrict__ W1Tb,
    const u16* __restrict__ loop1Tb, const float* __restrict__ b1,
    const int* __restrict__ src, const int* __restrict__ dst,
    const int* __restrict__ perm, const int* __restrict__ seg_off,
    int* __restrict__ cur_dst, int* __restrict__ srel,
    u16* __restrict__ msgbuf, u16* __restrict__ agg1b){
  __shared__ __align__(16) u16 Bls[64][136];    // 17408 B
  __shared__ __align__(16) u16 msg[128][72];    // 18432 B
  __shared__ int posIds[128];
  int tid = threadIdx.x, lane = tid & 63, w = tid >> 6;
  int r16 = lane & 15, c4 = lane >> 4;

  if (blockIdx.x >= NSEG) {                     // ---- self-loop path ----
    int base = (blockIdx.x - NSEG) * 64;
    { int j = tid >> 2, sg = tid & 3;
      const uint4* g = (const uint4*)(loop1Tb + j * 128) + sg * 4;
      uint4* d = (uint4*)&Bls[j][sg * 32];
      d[0] = g[0]; d[1] = g[1]; d[2] = g[2]; d[3] = g[3]; }
    int arow = base + w * 16 + r16; if (arow >= N_NODES) arow = N_NODES - 1;
    sfrag aF[4];
    #pragma unroll
    for (int kk = 0; kk < 4; ++kk)
      aF[kk] = *(const sfrag*)(featb + (size_t)arow * D_IN + kk * 32 + c4 * 8);
    __syncthreads();
    #pragma unroll
    for (int ct = 0; ct < 4; ++ct) {
      f32x4 acc = {0.f, 0.f, 0.f, 0.f};
      #pragma unroll
      for (int kk = 0; kk < 4; ++kk) {
        sfrag bF = *(const sfrag*)&Bls[ct * 16 + r16][kk * 32 + c4 * 8];
        acc = __builtin_amdgcn_mfma_f32_16x16x32_bf16(aF[kk], bF, acc, 0, 0, 0);
      }
      int col = ct * 16 + r16;
      float bias = b1[col];
      #pragma unroll
      for (int reg = 0; reg < 4; ++reg) {
        float v = acc[reg] + bias;
        float o = __shfl_xor(v, 1);
        if (!(lane & 1)) {
          int orow = w * 16 + c4 * 4 + reg;     // block-local 0..63
          *(u32*)&msg[orow][col] = pack2(v, o);
        }
      }
    }
    __syncthreads();
    { int row = tid >> 2, q = tid & 3;          // 4 threads/row, 32B each
      int n = base + row;
      if (n < N_NODES) {
        uint4 a0 = ((const uint4*)&msg[row][0])[q * 2];
        uint4 a1 = ((const uint4*)&msg[row][0])[q * 2 + 1];
        uint4* d = (uint4*)(agg1b + (size_t)n * D_HID + q * 16);
        d[0] = a0; d[1] = a1;
      } }
    return;
  }

  // ---- segment path ----
  const int q8 = NSEG >> 3, r8 = NSEG & 7;      // 232, 6 — bijective XCD chunk map
  int xcd = blockIdx.x & 7, cidx = blockIdx.x >> 3;
  int seg = (xcd < r8 ? xcd * (q8 + 1) : r8 * (q8 + 1) + (xcd - r8) * q8) + cidx;
  int ts = seg_off[seg], c = seg_off[seg + 1] - ts;
  if (c == 0) return;
  int rel = seg - (seg / N_RELS) * N_RELS;      // seg % 19

  { // B tile: W1Tb[rel], 64 x 128 bf16 (staged ONCE per segment)
    int j = tid >> 2, sg = tid & 3;
    const uint4* g = (const uint4*)(W1Tb + ((size_t)rel * 64 + j) * 128) + sg * 4;
    uint4* d = (uint4*)&Bls[j][sg * 32];
    d[0] = g[0]; d[1] = g[1]; d[2] = g[2]; d[3] = g[3];
  }

  sfrag aN[2][4]; int nextPos;
  gather_tile(featb, src, dst, perm, cur_dst, srel, ts, c, 0, rel,
              tid, w, r16, c4, aN, nextPos);
  __syncthreads();                              // B ready (gathers keep flying)

  for (int t0 = 0; t0 < c; t0 += 128) {
    sfrag aC[2][4];
    #pragma unroll
    for (int mt = 0; mt < 2; ++mt)
      #pragma unroll
      for (int kk = 0; kk < 4; ++kk) aC[mt][kk] = aN[mt][kk];
    int curPos = nextPos;
    if (t0 + 128 < c)                           // issue NEXT tile's gathers + atomic
      gather_tile(featb, src, dst, perm, cur_dst, srel, ts, c, t0 + 128, rel,
                  tid, w, r16, c4, aN, nextPos);
    // MFMA on current tile
    #pragma unroll
    for (int ct = 0; ct < 4; ++ct) {
      sfrag bF[4];
      #pragma unroll
      for (int kk = 0; kk < 4; ++kk)
        bF[kk] = *(const sfrag*)&Bls[ct * 16 + r16][kk * 32 + c4 * 8];
      #pragma unroll
      for (int mt = 0; mt < 2; ++mt) {
        f32x4 acc = {0.f, 0.f, 0.f, 0.f};
        #pragma unroll
        for (int kk = 0; kk < 4; ++kk)
          acc = __builtin_amdgcn_mfma_f32_16x16x32_bf16(aC[mt][kk], bF[kk], acc, 0, 0, 0);
        #pragma unroll
        for (int reg = 0; reg < 4; ++reg) {
          float v = acc[reg];
          float o = __shfl_xor(v, 1);
          if (!(lane & 1)) {
            int orow = w * 32 + mt * 16 + c4 * 4 + reg;
            *(u32*)&msg[orow][ct * 16 + r16] = pack2(v, o);
          }
        }
      }
    }
    if (tid < 128) posIds[tid] = curPos;
    __syncthreads();
    { int row = tid >> 1, half = tid & 1;       // coalesced 64B/thread writeout
      int pos = posIds[row];
      if (pos >= 0) {
        const uint4* mr = (const uint4*)&msg[row][half * 32];
        uint4* d = (uint4*)(msgbuf + (size_t)pos * D_HID + half * 32);
        d[0] = mr[0]; d[1] = mr[1]; d[2] = mr[2]; d[3] = mr[3];
      } }
    __syncthreads();                            // msg free for next tile
  }
}

// Fused: message aggregation (one node per wave) + self-loop + relu -> h1b,
// plus layer-2 self-loop: out[n,:] = h1 @ loop2 + b2 (full init of out).
__global__ __launch_bounds__(256) void k_agg_relu_self2(
    const u16* __restrict__ msgbuf, const int* __restrict__ dstart,
    const int* __restrict__ cnt, const u16* __restrict__ agg1b,
    const float* __restrict__ loop2, const float* __restrict__ b2,
    u16* __restrict__ h1b, float* __restrict__ out){
  int wv = threadIdx.x >> 6, lane = threadIdx.x & 63;
  int n = blockIdx.x * 4 + wv;
  int s = dstart[n], epos = s + cnt[n];
  int h = lane >> 5, c = lane & 31;
  float a0 = 0.f, a1 = 0.f;
  for (int i = s + h; i < epos; i += 2) {
    u32 v = ((const u32*)msgbuf)[(size_t)i * 32 + c];
    a0 += bf2f((u16)(v & 0xffffu));
    a1 += bf2f((u16)(v >> 16));
  }
  a0 += __shfl_down(a0, 32);
  a1 += __shfl_down(a1, 32);
  float p0 = 0.f, p1 = 0.f;
  if (h == 0) {
    u32 sv = ((const u32*)agg1b)[(size_t)n * 32 + c];
    float v0 = a0 + bf2f((u16)(sv & 0xffffu));
    float v1 = a1 + bf2f((u16)(sv >> 16));
    v0 = v0 > 0.f ? v0 : 0.f;
    v1 = v1 > 0.f ? v1 : 0.f;
    ((u32*)h1b)[(size_t)n * 32 + c] = (u32)f2bf(v0) | ((u32)f2bf(v1) << 16);
    float2 w0 = ((const float2*)loop2)[2 * c];
    float2 w1 = ((const float2*)loop2)[2 * c + 1];
    p0 = v0 * w0.x + v1 * w1.x;
    p1 = v0 * w0.y + v1 * w1.y;
  }
  #pragma unroll
  for (int off = 16; off; off >>= 1) {
    p0 += __shfl_down(p0, off);
    p1 += __shfl_down(p1, off);
  }
  if (lane == 0) {
    out[n * 2]     = p0 + b2[0];
    out[n * 2 + 1] = p1 + b2[1];
  }
}

// Layer-2 dense per-rel transform of ALL nodes: T2[n][2r+o] = sum_k h1[n,k]*W2[r,k,o].
__global__ __launch_bounds__(256) void k_t2(
    const u16* __restrict__ h1b, const u16* __restrict__ W2allT,
    float* __restrict__ T2){
  __shared__ __align__(16) u16 Bls[48][72];
  int tid = threadIdx.x, lane = tid & 63, w = tid >> 6;
  int r16 = lane & 15, c4 = lane >> 4;
  for (int idx = tid; idx < 48 * 8; idx += 256) {
    int row = idx >> 3, q = idx & 7;
    ((uint4*)&Bls[row][0])[q] = ((const uint4*)W2allT)[idx];
  }
  int base = blockIdx.x * 64;
  int arow = base + w * 16 + r16; if (arow >= N_NODES) arow = N_NODES - 1;
  sfrag aF[2];
  #pragma unroll
  for (int kk = 0; kk < 2; ++kk)
    aF[kk] = *(const sfrag*)(h1b + (size_t)arow * D_HID + kk * 32 + c4 * 8);
  __syncthreads();
  #pragma unroll
  for (int ct = 0; ct < 3; ++ct) {
    f32x4 acc = {0.f, 0.f, 0.f, 0.f};
    #pragma unroll
    for (int kk = 0; kk < 2; ++kk) {
      sfrag bF = *(const sfrag*)&Bls[ct * 16 + r16][kk * 32 + c4 * 8];
      acc = __builtin_amdgcn_mfma_f32_16x16x32_bf16(aF[kk], bF, acc, 0, 0, 0);
    }
    int col = ct * 16 + r16;
    if (col < N_RELS * D_OUT) {
      #pragma unroll
      for (int reg = 0; reg < 4; ++reg) {
        int orow = base + w * 16 + c4 * 4 + reg;
        if (orow < N_NODES) T2[(size_t)orow * 40 + col] = acc[reg];
      }
    }
  }
}

// Layer-2 finish, atomic-free: one wave per node; gather T2[src][2r..] per slot.
__global__ __launch_bounds__(256) void k_fin(
    const float* __restrict__ T2, const int* __restrict__ srel,
    const int* __restrict__ dstart, const int* __restrict__ cnt,
    float* __restrict__ out){
  int wv = threadIdx.x >> 6, lane = threadIdx.x & 63;
  int n = blockIdx.x * 4 + wv;
  int s = dstart[n], c = cnt[n];
  float ax = 0.f, ay = 0.f;
  for (int i = lane; i < c; i += 64) {
    int sr = srel[s + i];
    const float* p = T2 + (size_t)(sr >> 5) * 40 + (sr & 31) * 2;
    ax += p[0]; ay += p[1];
  }
  #pragma unroll
  for (int off = 32; off; off >>= 1) {
    ax += __shfl_down(ax, off);
    ay += __shfl_down(ay, off);
  }
  if (lane == 0) {
    out[n * 2]     += ax;
    out[n * 2 + 1] += ay;
  }
}

extern "C" void kernel_launch(void* const* d_in, const int* in_sizes, int n_in,
                              void* d_out, int out_size, void* d_ws, size_t ws_size,
                              hipStream_t stream){
  const float* feat  = (const float*)d_in[0];
  const float* W1    = (const float*)d_in[1];
  const float* loop1 = (const float*)d_in[2];
  const float* b1    = (const float*)d_in[3];
  const float* W2    = (const float*)d_in[4];
  const float* loop2 = (const float*)d_in[5];
  const float* b2    = (const float*)d_in[6];
  const int* src     = (const int*)d_in[7];
  const int* dst     = (const int*)d_in[8];
  const int* et      = (const int*)d_in[9];
  float* out = (float*)d_out;

  // workspace layout (16B-aligned), ~108.4 MB total.
  char* w = (char*)d_ws;
  u16*   W1Tb     = (u16*)(w);                   //  311296
  u16*   W2allT   = (u16*)(w + 311296);          //    6144
  u16*   loop1Tb  = (u16*)(w + 317440);          //   16384
  int*   seg_hist = (int*)(w + 333824);          //  119168 (1862 x 64B-padded) ┐
  int*   gcnt     = (int*)(w + 452992);          //      64                     ├ memset
  int*   hist_dst = (int*)(w + 453056);          //  200000                     ┘
  int*   seg_off  = (int*)(w + 653056);          //    7488
  int*   cur_seg  = (int*)(w + 660544);          //  119168 (64B-padded)
  int*   dstart   = (int*)(w + 779712);          //  200000
  int*   cur_dst  = (int*)(w + 979712);          //  200000
  int*   perm     = (int*)(w + 1179712);         // 2400000
  int*   srel     = (int*)(w + 3579712);         // 2400000
  u16*   featb    = (u16*)(w + 5979712);         // 12.8 MB (T2f aliases; featb dead after k_se1)
  float* T2f      = (float*)(w + 5979712);       //  8.0 MB (50000 x 40 f32)
  u16*   agg1b    = (u16*)(w + 18779712);        //  6.4 MB
  u16*   h1b      = (u16*)(w + 25179712);        //  6.4 MB
  u16*   msgbuf   = (u16*)(w + 31579712);        // 76.8 MB -> 108379712

  hipMemsetAsync(w + 333824, 0, 319232, stream);
  k_fused_pre     <<<6250, 256, 0, stream>>>(feat, featb, src, et, dst, seg_hist, hist_dst);
  k_alloc_scan    <<<197 + PREP_BLOCKS, 256, 0, stream>>>(
                      hist_dst, dstart, cur_dst, gcnt, seg_hist, seg_off, cur_seg,
                      W1, loop1, W2, W1Tb, loop1Tb, W2allT);
  k_scatter       <<<2344,  256, 0, stream>>>(src, et, cur_seg, perm);
  k_se1           <<<NSEG + SL_BLOCKS, 256, 0, stream>>>(
                      featb, W1Tb, loop1Tb, b1, src, dst, perm, seg_off,
                      cur_dst, srel, msgbuf, agg1b);
  k_agg_relu_self2<<<12500, 256, 0, stream>>>(msgbuf, dstart, hist_dst, agg1b,
                                              loop2, b2, h1b, out);
  k_t2            <<<SL_BLOCKS, 256, 0, stream>>>(h1b, W2allT, T2f);
  k_fin           <<<12500, 256, 0, stream>>>(T2f, srel, dstart, hist_dst, out);
}